// Round 9
// baseline (494.663 us; speedup 1.0000x reference)
//
#include <hip/hip_runtime.h>
#include <cstdint>

#define BB 256
#define TT 1000
#define DD 256
#define SS 10
#define HH 64
#define CC 100

// ---------------------------------------------------------------------------
// Kernel 1: input projection  xp[b,t,h] = 2*(x . W_ih + b_ih + b_hh)
// kc chunk 32 (LDS 18.4 KB -> ~8 blocks/CU for latency hiding).
// ---------------------------------------------------------------------------
__global__ __launch_bounds__(256) void proj_kernel(
    const float* __restrict__ x, const float* __restrict__ W_ih,
    const float* __restrict__ b_ih, const float* __restrict__ b_hh,
    float* __restrict__ xp) {
  __shared__ float As[64][36];
  __shared__ float Bs[64][36];
  const int s = blockIdx.y;
  const int r0 = blockIdx.x * 64;
  const int tid = threadIdx.x;
  const int ty = tid >> 4, tx = tid & 15;
  const int ty4 = ty * 4, tx4 = tx * 4;
  float acc[4][4] = {{0.f, 0.f, 0.f, 0.f}};

  for (int kc = 0; kc < 8; ++kc) {
    // stage 64 rows x 32 k: 512 float4 / 256 thr = 2 each per array
#pragma unroll
    for (int m = 0; m < 2; ++m) {
      int f = m * 256 + tid;
      int row = f >> 3, kq = f & 7;
      int r = r0 + row;
      int b = r / CC, c = r - b * CC;
      const float4 av = *(const float4*)(
          x + ((size_t)b * TT + s * CC + c) * DD + kc * 32 + kq * 4);
      *(float4*)&As[row][kq * 4] = av;
      const float4 wv = *(const float4*)(
          W_ih + ((size_t)s * HH + row) * DD + kc * 32 + kq * 4);
      *(float4*)&Bs[row][kq * 4] = wv;
    }
    __syncthreads();
#pragma unroll
    for (int k = 0; k < 32; k += 4) {
      float4 a[4], w[4];
#pragma unroll
      for (int i = 0; i < 4; ++i) a[i] = *(const float4*)&As[ty4 + i][k];
#pragma unroll
      for (int j = 0; j < 4; ++j) w[j] = *(const float4*)&Bs[tx4 + j][k];
#pragma unroll
      for (int i = 0; i < 4; ++i)
#pragma unroll
        for (int j = 0; j < 4; ++j)
          acc[i][j] += a[i].x * w[j].x + a[i].y * w[j].y +
                       a[i].z * w[j].z + a[i].w * w[j].w;
    }
    __syncthreads();
  }

  const float4 b1 = *(const float4*)(b_ih + s * HH + tx4);
  const float4 b2 = *(const float4*)(b_hh + s * HH + tx4);
#pragma unroll
  for (int i = 0; i < 4; ++i) {
    int r = r0 + ty4 + i;
    int b = r / CC, c = r - b * CC;
    float4 o;
    o.x = 2.f * (acc[i][0] + b1.x + b2.x);
    o.y = 2.f * (acc[i][1] + b1.y + b2.y);
    o.z = 2.f * (acc[i][2] + b1.z + b2.z);
    o.w = 2.f * (acc[i][3] + b1.w + b2.w);
    *(float4*)(xp + ((size_t)b * TT + s * CC + c) * HH + tx4) = o;
  }
}

// ---------------------------------------------------------------------------
// Kernel 2: recurrence only (probe<0>-anchored). One wave per batch element.
// - compiler-scheduled 16x ds_read_b128 broadcast from a single hrow
// - NO sched_barrier, NO inline asm, NO fused head (R6 probe: these cost
//   ~60-100us by blocking overlap into the DS-wait shadow)
// - h stored per step to ys (global, coalesced, fire-and-forget, off-chain)
// - ys ALIASES xp: slot (b,t) is last read >=10 steps before it is written
//   (group prefetch reads ahead), so write-after-read is safe.
// ---------------------------------------------------------------------------
__global__ __launch_bounds__(64, 1) void rnn_kernel(
    const float* __restrict__ xp, const float* __restrict__ W_hh,
    float* __restrict__ ys) {
  __shared__ float hrow[68];
  const int b = blockIdx.x;
  const int lane = threadIdx.x;

  hrow[lane] = 0.f;  // h0 = 0

  float W[64];
  float h = 0.f;
  float4 hv[16];
  for (int s = 0; s < SS; ++s) {
    const float* wr = W_hh + ((size_t)s * HH + lane) * HH;
#pragma unroll
    for (int j = 0; j < 64; j += 4) {
      float4 v = *(const float4*)(wr + j);
      W[j] = 2.f * v.x; W[j + 1] = 2.f * v.y;
      W[j + 2] = 2.f * v.z; W[j + 3] = 2.f * v.w;
    }
    const float* xps = xp + ((size_t)b * TT + s * CC) * HH + lane;
    float* yss = ys + ((size_t)b * TT + s * CC) * HH + lane;

    float xA[10], xB[10];
#pragma unroll
    for (int u = 0; u < 10; ++u) xA[u] = xps[u * HH];

    for (int gg = 0; gg < 5; ++gg) {
      const int base = gg * 20;
      // prefetch next 10 (unconditional coalesced loads, off-chain)
#pragma unroll
      for (int u = 0; u < 10; ++u) xB[u] = xps[(base + 10 + u) * HH];
#pragma unroll
      for (int u = 0; u < 10; ++u) {
        const int c = base + u;
#pragma unroll
        for (int j4 = 0; j4 < 16; ++j4)
          hv[j4] = *(const float4*)&hrow[j4 * 4];
        float a0 = xA[u], a1 = 0.f, a2 = 0.f, a3 = 0.f;
#pragma unroll
        for (int j4 = 0; j4 < 16; ++j4) {
          a0 += W[j4 * 4 + 0] * hv[j4].x;
          a1 += W[j4 * 4 + 1] * hv[j4].y;
          a2 += W[j4 * 4 + 2] * hv[j4].z;
          a3 += W[j4 * 4 + 3] * hv[j4].w;
        }
        float z2 = (a0 + a1) + (a2 + a3);  // = 2z (prescaled)
        float e = __expf(z2);
        h = 1.f - 2.f * __builtin_amdgcn_rcpf(e + 1.f);
        hrow[lane] = h;
        yss[c * HH] = h;  // fire-and-forget, coalesced 256B
      }
      // prefetch following 10 into xA (clamped dummy on last group)
#pragma unroll
      for (int u = 0; u < 10; ++u) {
        int ci = base + 20 + u;
        if (ci > CC - 1) ci = CC - 1;
        xA[u] = xps[ci * HH];
      }
#pragma unroll
      for (int u = 0; u < 10; ++u) {
        const int c = base + 10 + u;
#pragma unroll
        for (int j4 = 0; j4 < 16; ++j4)
          hv[j4] = *(const float4*)&hrow[j4 * 4];
        float a0 = xB[u], a1 = 0.f, a2 = 0.f, a3 = 0.f;
#pragma unroll
        for (int j4 = 0; j4 < 16; ++j4) {
          a0 += W[j4 * 4 + 0] * hv[j4].x;
          a1 += W[j4 * 4 + 1] * hv[j4].y;
          a2 += W[j4 * 4 + 2] * hv[j4].z;
          a3 += W[j4 * 4 + 3] * hv[j4].w;
        }
        float z2 = (a0 + a1) + (a2 + a3);
        float e = __expf(z2);
        h = 1.f - 2.f * __builtin_amdgcn_rcpf(e + 1.f);
        hrow[lane] = h;
        yss[c * HH] = h;
      }
    }
  }
}

// ---------------------------------------------------------------------------
// Kernel 3: head  y[b,t] = sigmoid(ys[b,t,:] . fc_w[s(t)] + fc_b[s(t)])
// Memory-bound: 65.5 MB read, 1 MB write. One thread per (b,t).
// ---------------------------------------------------------------------------
__global__ __launch_bounds__(256) void head_kernel(
    const float* __restrict__ ys, const float* __restrict__ fc_w,
    const float* __restrict__ fc_b, float* __restrict__ y) {
  const int idx = blockIdx.x * 256 + threadIdx.x;  // = b*TT + t
  const int t = idx % TT;
  const int s = t / CC;
  const float* base = ys + (size_t)idx * HH;
  const float* fw = fc_w + s * HH;
  float z = fc_b[s];
#pragma unroll
  for (int i = 0; i < 16; ++i) {
    const float4 a = *(const float4*)(base + i * 4);
    const float4 w = *(const float4*)(fw + i * 4);
    z += a.x * w.x + a.y * w.y + a.z * w.z + a.w * w.w;
  }
  y[idx] = __builtin_amdgcn_rcpf(1.f + __expf(-z));
}

extern "C" void kernel_launch(void* const* d_in, const int* in_sizes, int n_in,
                              void* d_out, int out_size, void* d_ws,
                              size_t ws_size, hipStream_t stream) {
  const float* x    = (const float*)d_in[0];
  const float* W_ih = (const float*)d_in[1];
  const float* W_hh = (const float*)d_in[2];
  const float* b_ih = (const float*)d_in[3];
  const float* b_hh = (const float*)d_in[4];
  const float* fc_w = (const float*)d_in[5];
  const float* fc_b = (const float*)d_in[6];
  float* y  = (float*)d_out;
  float* xp = (float*)d_ws;  // [B][T][H] fp32 = 65.5 MB
  float* ys = xp;            // aliases xp: slot (b,t) read >=10 steps before written

  proj_kernel<<<dim3(400, 10), 256, 0, stream>>>(x, W_ih, b_ih, b_hh, xp);
  rnn_kernel<<<256, 64, 0, stream>>>(xp, W_hh, ys);
  head_kernel<<<1000, 256, 0, stream>>>(ys, fc_w, fc_b, y);
}